// Round 11
// baseline (689.407 us; speedup 1.0000x reference)
//
#include <hip/hip_runtime.h>
#include <hip/hip_bf16.h>

// EquivariantUpdate, round 11.
// prep -> pack_bmat -> k0_proj -> k1_gemm -> k3_atom -> k2_frag.
// K3 fixes vs r10 (counters: 1.39M LDS bank conflicts from the PB table
// [256B rows -> all row-starts on bank 0, 32 lanes x 32 random rows], VGPR
// 256 -> 1 block/CU -> latency-exposed): (1) PB read from GLOBAL (25KB,
// L1-resident, no bank-conflict path); (2) z1-compute interleaved with
// layer-2 MFMA per kc (wb transient) -> ~90 arch regs; (3) launch_bounds
// (256,2) -> 128 arch + 128 AGPR per wave -> 16 waves/CU.

typedef __attribute__((ext_vector_type(8))) short bfrag8;
typedef __attribute__((ext_vector_type(16))) float f32x16;
typedef __attribute__((ext_vector_type(4))) float f32x4v;

#define MFMA32(A, B, C) __builtin_amdgcn_mfma_f32_32x32x16_bf16((A), (B), (C), 0, 0, 0)

__device__ __forceinline__ f32x16 zero16() {
  f32x16 v;
#pragma unroll
  for (int i = 0; i < 16; ++i) v[i] = 0.0f;
  return v;
}

__device__ __forceinline__ unsigned short bf16bits(float x) {
  __hip_bfloat16 b = __float2bfloat16(x);
  unsigned short u;
  __builtin_memcpy(&u, &b, 2);
  return u;
}

__device__ __forceinline__ float b2f(unsigned short u) {
  unsigned x = ((unsigned)u) << 16;
  float f;
  __builtin_memcpy(&f, &x, 4);
  return f;
}

__device__ __forceinline__ unsigned pk2(float lo, float hi) {
  return (unsigned)bf16bits(lo) | ((unsigned)bf16bits(hi) << 16);
}

__device__ __forceinline__ bfrag8 ldfrag(const unsigned short* p) {
  return *reinterpret_cast<const bfrag8*>(p);
}

__device__ __forceinline__ bfrag8 frag4(unsigned f0, unsigned f1, unsigned f2, unsigned f3) {
  union { unsigned u[4]; bfrag8 v; } q;
  q.u[0] = f0; q.u[1] = f1; q.u[2] = f2; q.u[3] = f3;
  return q.v;
}

__device__ __forceinline__ float silu_f(float x) { return x / (1.0f + __expf(-x)); }

// ---------------- prep ----------------
// Segments: [cvt h_a][hfp][5x pack_wT][PB][ew][zero agg]
__global__ __launch_bounds__(256) void prep_kernel(
    const float* __restrict__ h_a, const float* __restrict__ bond,
    const float* __restrict__ h_f,
    const float* __restrict__ aW1, const float* __restrict__ ab1,
    const float* __restrict__ aW2,
    const float* __restrict__ fW1, const float* __restrict__ fW2,
    unsigned short* __restrict__ h_bf,
    float* __restrict__ hfp,
    unsigned short* __restrict__ W1aT, unsigned short* __restrict__ W1bT,
    unsigned short* __restrict__ W2T,
    unsigned short* __restrict__ fW1aT, unsigned short* __restrict__ fW2T,
    unsigned short* __restrict__ PBg, unsigned* __restrict__ ewg,
    float* __restrict__ agg,
    int N, int NB, int F) {
  const int t = threadIdx.x;
  int bid = blockIdx.x;
  const int G_A = (N * 16 + 255) >> 8;
  const int G_H = (F + 1) >> 1;
  const int G_PB = (NB * 128 + 255) >> 8;

  if (bid < G_A) {
    // bf16 convert, permuted row layout: dst[row*128 + h*64 + kc*8 + j]
    int idx = bid * 256 + t;
    if (idx < N * 16) {
      int row = idx >> 4, g = idx & 15;
      int h = g & 1, kc = g >> 1;
      const f32x4v* s = reinterpret_cast<const f32x4v*>(h_a + (size_t)row * 128 + g * 8);
      f32x4v v0 = s[0], v1 = s[1];
      unsigned* d = reinterpret_cast<unsigned*>(h_bf + (size_t)row * 128 + h * 64 + kc * 8);
      d[0] = pk2(v0[0], v0[1]);
      d[1] = pk2(v0[2], v0[3]);
      d[2] = pk2(v1[0], v1[1]);
      d[3] = pk2(v1[2], v1[3]);
    }
    return;
  }
  bid -= G_A;
  if (bid < G_H) {
    int f = bid * 2 + (t >> 7), n = t & 127;
    if (f < F) {
      float acc = 0.0f;
#pragma unroll 8
      for (int k = 0; k < 128; ++k)
        acc += h_f[(size_t)f * 128 + k] * fW1[(size_t)(128 + k) * 128 + n];
      hfp[(size_t)f * 128 + n] = acc;
    }
    return;
  }
  bid -= G_H;
  if (bid < 5 * 64) {
    int p = bid >> 6;
    int tt = (bid & 63) * 256 + t;
    int j = tt & 7, l = (tt >> 3) & 63, rem = tt >> 9;
    int nt = rem & 3, kc = rem >> 2;
    int k = kc * 16 + ((l >> 5) << 3) + j;
    int n = nt * 32 + (l & 31);
    const float* W;
    unsigned short* D;
    switch (p) {
      case 0: W = aW1;             D = W1aT;  break;
      case 1: W = aW1 + 128 * 128; D = W1bT;  break;
      case 2: W = aW2;             D = W2T;   break;
      case 3: W = fW1;             D = fW1aT; break;
      default: W = fW2;            D = fW2T;  break;
    }
    D[tt] = bf16bits(W[(size_t)k * 128 + n]);
    return;
  }
  bid -= 5 * 64;
  if (bid < G_PB) {
    // PB[t][n] = sum_m bond[t][m]*aW1[258+m][n] + ab1[n], stored bf16 permuted
    int idx = bid * 256 + t;
    if (idx < NB * 128) {
      int ty = idx >> 7, n = idx & 127;
      float acc = ab1[n];
#pragma unroll 8
      for (int m = 0; m < 128; ++m)
        acc += bond[(size_t)ty * 128 + m] * aW1[(size_t)(258 + m) * 128 + n];
      PBg[(size_t)ty * 128 + ((n >> 3) & 1) * 64 + (n >> 4) * 8 + (n & 7)] = bf16bits(acc);
    }
    return;
  }
  bid -= G_PB;
  if (bid < 1) {
    // ew table: pair (w1e0[k], w1e1[k]) bf16x2, fragment order
    if (t < 128) {
      int k = t;
      unsigned u = pk2(aW1[(size_t)256 * 128 + k], aW1[(size_t)257 * 128 + k]);
      ewg[((k >> 4) * 2 + ((k >> 3) & 1)) * 8 + (k & 7)] = u;
    }
    return;
  }
  bid -= 1;
  {
    int i4 = (bid * 256 + t) * 4;
    if (i4 + 3 < N * 3) {
      *reinterpret_cast<f32x4v*>(agg + i4) = f32x4v{0.f, 0.f, 0.f, 0.f};
    } else {
      for (int c = 0; c < 4; ++c)
        if (i4 + c < N * 3) agg[i4 + c] = 0.0f;
    }
  }
}

// K1's A operand: Bmat^T frags.
__global__ void pack_bmat_kernel(const float* __restrict__ hfp, const float* __restrict__ x_f,
                                 unsigned short* __restrict__ dst, int total) {
  int t = blockIdx.x * blockDim.x + threadIdx.x;
  if (t >= total) return;
  int j = t & 7, l = (t >> 3) & 63, rem = t >> 9;
  int nt = rem % 5, kc = rem / 5;
  int k = kc * 16 + ((l >> 5) << 3) + j;
  int n = nt * 32 + (l & 31);
  float v;
  if (n < 128) v = hfp[(size_t)k * 128 + n];
  else if (n < 131) v = x_f[(size_t)k * 3 + (n - 128)];
  else v = 0.0f;
  dst[t] = bf16bits(v);
}

// ---------------- k0_proj: P1 = W1a^T h, P2 = W1b^T h (bf16, permuted) ----------------
__global__ __launch_bounds__(256) void k0_proj(
    const unsigned short* __restrict__ h_bf,
    const unsigned short* __restrict__ W1aT, const unsigned short* __restrict__ W1bT,
    unsigned short* __restrict__ P1bf, unsigned short* __restrict__ P2bf,
    int N) {
  const int lane = threadIdx.x & 63;
  const int w = threadIdx.x >> 6;
  const int h = lane >> 5;
  const int ln = lane & 31;
  const int node = blockIdx.x * 128 + w * 32 + ln;
  const int nc = (node < N) ? node : (N - 1);
  const unsigned short* hp = h_bf + (size_t)nc * 128 + h * 64;

#pragma unroll
  for (int p = 0; p < 2; ++p) {
    const unsigned short* WT = p ? W1bT : W1aT;
    unsigned short* dst = p ? P2bf : P1bf;
    f32x16 acc[4];
#pragma unroll
    for (int q = 0; q < 4; ++q) acc[q] = zero16();
#pragma unroll
    for (int kc = 0; kc < 8; ++kc) {
      bfrag8 b = ldfrag(hp + kc * 8);
      const unsigned short* wp = WT + ((size_t)(kc * 4) * 64 + lane) * 8;
#pragma unroll
      for (int nt = 0; nt < 4; ++nt) acc[nt] = MFMA32(ldfrag(wp + nt * 512), b, acc[nt]);
    }
    if (node < N) {
#pragma unroll
      for (int nt = 0; nt < 4; ++nt)
#pragma unroll
        for (int q = 0; q < 4; ++q) {
          union { unsigned u[2]; unsigned long long ull; } pr;
          pr.u[0] = pk2(acc[nt][4 * q + 0], acc[nt][4 * q + 1]);
          pr.u[1] = pk2(acc[nt][4 * q + 2], acc[nt][4 * q + 3]);
          int off = (q & 1) * 64 + (nt * 2 + (q >> 1)) * 8 + 4 * h;
          *reinterpret_cast<unsigned long long*>(dst + (size_t)node * 128 + off) = pr.ull;
        }
    }
  }
}

// ---------------- K1: barrier-free wave-private streaming GEMM ----------------
__global__ __launch_bounds__(256) void k1_gemm(
    const float* __restrict__ bm, const unsigned short* __restrict__ bmT,
    float* __restrict__ k1T, int N, int F) {
  __shared__ __align__(16) char lds[4][2][32 * 128];  // [wave][dbuf][4KB]
  const int t = threadIdx.x;
  const int lane = t & 63;
  const int w = t >> 6;
  const int h = lane >> 5;
  const int ln = lane & 31;
  const int m0w = blockIdx.x * 128 + w * 32;
  const int NT = (F + 63) >> 6;

  f32x16 acc[5];
#pragma unroll
  for (int i = 0; i < 5; ++i) acc[i] = zero16();

  int srow[8], sch[8];
  const float* sptr[8];
#pragma unroll
  for (int p = 0; p < 8; ++p) {
    int c = p * 64 + lane;
    srow[p] = c >> 4;
    sch[p] = c & 15;
    int gr = m0w + srow[p];
    if (gr >= N) gr = N - 1;
    sptr[p] = bm + (size_t)gr * F;
  }

  const int rsw = (ln & 7) << 4;

  f32x4v sregs[8];
#pragma unroll
  for (int p = 0; p < 8; ++p) {
    int gk = sch[p] * 4;
    if (gk > F - 4) gk = F - 4;
    sregs[p] = *reinterpret_cast<const f32x4v*>(sptr[p] + gk);
  }
#pragma unroll
  for (int p = 0; p < 8; ++p) {
    int byte = srow[p] * 128 + ((sch[p] * 8) ^ ((srow[p] & 7) << 4));
    union { unsigned u[2]; unsigned long long ull; } q;
    q.u[0] = pk2(sregs[p][0], sregs[p][1]);
    q.u[1] = pk2(sregs[p][2], sregs[p][3]);
    *reinterpret_cast<unsigned long long*>(&lds[w][0][byte]) = q.ull;
  }

  int cur = 0;
  for (int kt = 0; kt < NT; ++kt) {
    const bool more = (kt + 1 < NT);
    if (more) {
#pragma unroll
      for (int p = 0; p < 8; ++p) {
        int gk = (kt + 1) * 64 + sch[p] * 4;
        if (gk > F - 4) gk = F - 4;
        sregs[p] = *reinterpret_cast<const f32x4v*>(sptr[p] + gk);
      }
    }
    const int rem = (F - kt * 64) >> 4;
    const int kcN = rem < 4 ? rem : 4;
    if (kcN == 4) {
#pragma unroll
      for (int kc = 0; kc < 4; ++kc) {
        bfrag8 b = *reinterpret_cast<const bfrag8*>(
            &lds[w][cur][ln * 128 + ((kc * 32 + h * 16) ^ rsw)]);
        const unsigned short* wp = bmT + ((size_t)(kt * 4 + kc) * 5 * 64 + lane) * 8;
#pragma unroll
        for (int nt = 0; nt < 5; ++nt) acc[nt] = MFMA32(ldfrag(wp + nt * 512), b, acc[nt]);
      }
    } else {
      for (int kc = 0; kc < kcN; ++kc) {
        bfrag8 b = *reinterpret_cast<const bfrag8*>(
            &lds[w][cur][ln * 128 + ((kc * 32 + h * 16) ^ rsw)]);
        const unsigned short* wp = bmT + ((size_t)(kt * 4 + kc) * 5 * 64 + lane) * 8;
#pragma unroll
        for (int nt = 0; nt < 5; ++nt) acc[nt] = MFMA32(ldfrag(wp + nt * 512), b, acc[nt]);
      }
    }
    if (more) {
#pragma unroll
      for (int p = 0; p < 8; ++p) {
        int byte = srow[p] * 128 + ((sch[p] * 8) ^ ((srow[p] & 7) << 4));
        union { unsigned u[2]; unsigned long long ull; } q;
        q.u[0] = pk2(sregs[p][0], sregs[p][1]);
        q.u[1] = pk2(sregs[p][2], sregs[p][3]);
        *reinterpret_cast<unsigned long long*>(&lds[w][cur ^ 1][byte]) = q.ull;
      }
    }
    cur ^= 1;
  }

  const int m = m0w + ln;
  if (m < N) {
#pragma unroll
    for (int nt = 0; nt < 5; ++nt)
#pragma unroll
      for (int r = 0; r < 16; ++r) {
        int n = nt * 32 + (r & 3) + 8 * (r >> 2) + 4 * h;
        if (n < 131) k1T[(size_t)n * N + m] = acc[nt][r];
      }
  }
}

// ---------------- K3: edge MLP, precomputed layer-1, interleaved layer-2 ----------------
__global__ __launch_bounds__(256, 2) void k3_atom(
    const unsigned short* __restrict__ P1bf, const unsigned short* __restrict__ P2bf,
    const unsigned short* __restrict__ PBg, const unsigned* __restrict__ ewg,
    const unsigned short* __restrict__ W2T,
    const int* __restrict__ eidx, const int* __restrict__ etype,
    const float* __restrict__ eattr, const float* __restrict__ cda,
    const float* __restrict__ ab2, const float* __restrict__ aW3,
    float* __restrict__ agg, int E) {
  __shared__ unsigned ew_lds[128];  // 512B; reads are h-uniform -> broadcast
  if (threadIdx.x < 128) ew_lds[threadIdx.x] = ewg[threadIdx.x];
  __syncthreads();
  const uint4* ew4 = reinterpret_cast<const uint4*>(ew_lds);

  const int lane = threadIdx.x & 63;
  const int wid = threadIdx.x >> 6;
  const int h = lane >> 5;
  const int ln = lane & 31;
  const int nGroups = (E + 31) >> 5;
  const int stride = gridDim.x * 4;

  for (int g = blockIdx.x * 4 + wid; g < nGroups; g += stride) {
    const int e = g * 32 + ln;
    const bool valid = (e < E);
    const int ec = valid ? e : (E - 1);
    const int row = eidx[ec];
    const int col = eidx[(size_t)E + ec];
    const int typ = etype[ec];
    const float e0 = eattr[2 * (size_t)ec];
    const float e1 = eattr[2 * (size_t)ec + 1];

    // gather layer-1 projections (16 x 16B in flight)
    const unsigned short* pr = P1bf + (size_t)row * 128 + h * 64;
    const unsigned short* pc = P2bf + (size_t)col * 128 + h * 64;
    const unsigned short* pb = PBg + (size_t)typ * 128 + h * 64;  // 25KB, L1-hot
    bfrag8 fa[8], fb[8];
#pragma unroll
    for (int kc = 0; kc < 8; ++kc) fa[kc] = ldfrag(pr + kc * 8);
#pragma unroll
    for (int kc = 0; kc < 8; ++kc) fb[kc] = ldfrag(pc + kc * 8);

    f32x16 acc[4];
#pragma unroll
    for (int q = 0; q < 4; ++q) acc[q] = zero16();

    // per-kc: z1 = fa+fb+PB+e*w ; silu ; pack ; 4 MFMA (wb transient)
#pragma unroll
    for (int kc = 0; kc < 8; ++kc) {
      bfrag8 pbv = ldfrag(pb + kc * 8);
      uint4 ea = ew4[(kc * 2 + h) * 2 + 0];
      uint4 eb = ew4[(kc * 2 + h) * 2 + 1];
      unsigned ew[8] = {ea.x, ea.y, ea.z, ea.w, eb.x, eb.y, eb.z, eb.w};
      float s[8];
#pragma unroll
      for (int j = 0; j < 8; ++j) {
        float z = b2f((unsigned short)fa[kc][j]) + b2f((unsigned short)fb[kc][j]) +
                  b2f((unsigned short)pbv[j]) +
                  e0 * b2f((unsigned short)(ew[j] & 0xffffu)) +
                  e1 * b2f((unsigned short)(ew[j] >> 16));
        s[j] = silu_f(z);
      }
      bfrag8 b = frag4(pk2(s[0], s[1]), pk2(s[2], s[3]), pk2(s[4], s[5]), pk2(s[6], s[7]));
      const unsigned short* wp = W2T + ((size_t)(kc * 4) * 64 + lane) * 8;
#pragma unroll
      for (int nt = 0; nt < 4; ++nt) acc[nt] = MFMA32(ldfrag(wp + nt * 512), b, acc[nt]);
    }

    float part = 0.0f;
#pragma unroll
    for (int nt = 0; nt < 4; ++nt)
#pragma unroll
      for (int r = 0; r < 16; ++r) {
        int n = nt * 32 + (r & 3) + 8 * (r >> 2) + 4 * h;
        part += silu_f(acc[nt][r] + ab2[n]) * aW3[n];
      }
    float mv = part + __shfl_xor(part, 32);

    if (valid) {
      float tt = tanhf(mv) * 0.1f;  // *10 (COORDS_RANGE) / 100 (NORM_FACTOR)
      if (h == 0) {
        atomicAdd(agg + 3 * (size_t)row + 0, cda[3 * (size_t)ec + 0] * tt);
        atomicAdd(agg + 3 * (size_t)row + 1, cda[3 * (size_t)ec + 1] * tt);
      } else {
        atomicAdd(agg + 3 * (size_t)row + 2, cda[3 * (size_t)ec + 2] * tt);
      }
    }
  }
}

// ---------------- K2: fragment MLP + compose output ----------------
__global__ __launch_bounds__(256, 2) void k2_frag(
    const float* __restrict__ x_a, const unsigned short* __restrict__ h_bf,
    const float* __restrict__ k1T, const float* __restrict__ agg,
    const unsigned short* __restrict__ fW1aT, const unsigned short* __restrict__ fW2T,
    const float* __restrict__ fW1, const float* __restrict__ fb1,
    const float* __restrict__ fb2, const float* __restrict__ fW3,
    float* __restrict__ out, int N) {
  const int lane = threadIdx.x & 63;
  const int wid = threadIdx.x >> 6;
  const int h = lane >> 5;
  const int ln = lane & 31;
  const int i = blockIdx.x * 128 + wid * 32 + ln;
  const bool valid = (i < N);
  const int ic = valid ? i : (N - 1);

  float cd[3];
  float radial = 0.0f;
#pragma unroll
  for (int c = 0; c < 3; ++c) {
    float v = x_a[3 * (size_t)ic + c] - k1T[(size_t)(128 + c) * N + ic];
    cd[c] = v;
    radial += v * v;
  }

  f32x16 acc[4];
#pragma unroll
  for (int q = 0; q < 4; ++q) acc[q] = zero16();
  const unsigned short* hp = h_bf + (size_t)ic * 128 + h * 64;
#pragma unroll
  for (int kc = 0; kc < 8; ++kc) {
    bfrag8 b = ldfrag(hp + kc * 8);
    const unsigned short* wp = fW1aT + ((size_t)(kc * 4) * 64 + lane) * 8;
#pragma unroll
    for (int nt = 0; nt < 4; ++nt) acc[nt] = MFMA32(ldfrag(wp + nt * 512), b, acc[nt]);
  }

  unsigned wv[32];
#pragma unroll
  for (int nt = 0; nt < 4; ++nt)
#pragma unroll
    for (int p = 0; p < 8; ++p) {
      const int r0 = 2 * p;
      const int n0 = nt * 32 + (r0 & 3) + 8 * (r0 >> 2) + 4 * h;
      const int n1 = n0 + 1;
      float q0 = acc[nt][r0] + k1T[(size_t)n0 * N + ic]
               + radial * (fW1[(size_t)256 * 128 + n0] + fW1[(size_t)257 * 128 + n0]) + fb1[n0];
      float q1 = acc[nt][r0 + 1] + k1T[(size_t)n1 * N + ic]
               + radial * (fW1[(size_t)256 * 128 + n1] + fW1[(size_t)257 * 128 + n1]) + fb1[n1];
      wv[nt * 8 + p] = pk2(silu_f(q0), silu_f(q1));
    }

#pragma unroll
  for (int q = 0; q < 4; ++q) acc[q] = zero16();
#pragma unroll
  for (int kc = 0; kc < 8; ++kc) {
    const int base = (kc >> 1) * 8 + (kc & 1) * 4;
    unsigned a0 = wv[base + 0], a1 = wv[base + 1], a2 = wv[base + 2], a3 = wv[base + 3];
    unsigned s0 = (unsigned)__shfl_xor((int)a0, 32);
    unsigned s1 = (unsigned)__shfl_xor((int)a1, 32);
    unsigned s2 = (unsigned)__shfl_xor((int)a2, 32);
    unsigned s3 = (unsigned)__shfl_xor((int)a3, 32);
    bfrag8 b = frag4(h ? s2 : a0, h ? s3 : a1, h ? a2 : s0, h ? a3 : s1);
    const unsigned short* wp = fW2T + ((size_t)(kc * 4) * 64 + lane) * 8;
#pragma unroll
    for (int nt = 0; nt < 4; ++nt) acc[nt] = MFMA32(ldfrag(wp + nt * 512), b, acc[nt]);
  }

  float part = 0.0f;
#pragma unroll
  for (int nt = 0; nt < 4; ++nt)
#pragma unroll
    for (int r = 0; r < 16; ++r) {
      int n = nt * 32 + (r & 3) + 8 * (r >> 2) + 4 * h;
      part += silu_f(acc[nt][r] + fb2[n]) * fW3[n];
    }
  float mv = part + __shfl_xor(part, 32);

  if (valid && h == 0) {
    float nrm = sqrtf(radial + 1e-8f);
    float s = tanhf(mv) * 10.0f / (nrm + 1.0f);
#pragma unroll
    for (int c = 0; c < 3; ++c)
      out[3 * (size_t)i + c] = x_a[3 * (size_t)i + c] + cd[c] * s + agg[3 * (size_t)i + c];
  }
}

// ---------------- launch ----------------

extern "C" void kernel_launch(void* const* d_in, const int* in_sizes, int n_in,
                              void* d_out, int out_size, void* d_ws, size_t ws_size,
                              hipStream_t stream) {
  const float* h_a    = (const float*)d_in[0];
  const float* x_a    = (const float*)d_in[1];
  const int*   e_idx  = (const int*)d_in[2];
  const int*   e_type = (const int*)d_in[3];
  const float* e_attr = (const float*)d_in[4];
  const float* cda    = (const float*)d_in[5];
  const float* h_f    = (const float*)d_in[6];
  const float* x_f    = (const float*)d_in[7];
  const float* bm     = (const float*)d_in[8];
  const float* bond   = (const float*)d_in[9];
  const float* aW1    = (const float*)d_in[10];
  const float* ab1    = (const float*)d_in[11];
  const float* aW2    = (const float*)d_in[12];
  const float* ab2    = (const float*)d_in[13];
  const float* aW3    = (const float*)d_in[14];
  const float* fW1    = (const float*)d_in[15];
  const float* fb1    = (const float*)d_in[16];
  const float* fW2    = (const float*)d_in[17];
  const float* fb2    = (const float*)d_in[18];
  const float* fW3    = (const float*)d_in[19];
  float* out = (float*)d_out;

  const int N  = in_sizes[0] / 128;
  const int E  = in_sizes[2] / 2;
  const int F  = in_sizes[6] / 128;
  const int NB = in_sizes[9] / 128;
  const int KC = F / 16;

  char* wsp = (char*)d_ws;
  size_t off = 0;
  auto alloc = [&](size_t bytes) -> char* {
    char* p = wsp + off;
    off += (bytes + 255) & ~(size_t)255;
    return p;
  };
  unsigned short* h_bf  = (unsigned short*)alloc((size_t)N * 128 * 2);
  float*          hfp   = (float*)alloc((size_t)F * 128 * 4);
  unsigned short* bmT   = (unsigned short*)alloc((size_t)KC * 5 * 64 * 8 * 2);
  unsigned short* W1aT  = (unsigned short*)alloc(8 * 4 * 64 * 8 * 2);
  unsigned short* W1bT  = (unsigned short*)alloc(8 * 4 * 64 * 8 * 2);
  unsigned short* W2T   = (unsigned short*)alloc(8 * 4 * 64 * 8 * 2);
  unsigned short* fW1aT = (unsigned short*)alloc(8 * 4 * 64 * 8 * 2);
  unsigned short* fW2T  = (unsigned short*)alloc(8 * 4 * 64 * 8 * 2);
  unsigned short* PBg   = (unsigned short*)alloc((size_t)NB * 128 * 2);
  unsigned*       ewg   = (unsigned*)alloc(128 * 4);
  unsigned short* P1bf  = (unsigned short*)alloc((size_t)N * 128 * 2);
  unsigned short* P2bf  = (unsigned short*)alloc((size_t)N * 128 * 2);
  float*          k1T   = (float*)alloc((size_t)131 * N * 4);
  float*          agg   = (float*)alloc((size_t)N * 3 * 4);

  const int G_A  = (N * 16 + 255) >> 8;
  const int G_H  = (F + 1) >> 1;
  const int G_PB = (NB * 128 + 255) >> 8;
  const int G_Z  = (N * 3 + 1023) >> 10;
  prep_kernel<<<G_A + G_H + 5 * 64 + G_PB + 1 + G_Z, 256, 0, stream>>>(
      h_a, bond, h_f, aW1, ab1, aW2, fW1, fW2,
      h_bf, hfp, W1aT, W1bT, W2T, fW1aT, fW2T, PBg, ewg, agg,
      N, NB, F);

  {
    int total = KC * 5 * 64 * 8;
    pack_bmat_kernel<<<(total + 255) / 256, 256, 0, stream>>>(hfp, x_f, bmT, total);
  }

  k0_proj<<<(N + 127) / 128, 256, 0, stream>>>(h_bf, W1aT, W1bT, P1bf, P2bf, N);

  k1_gemm<<<(N + 127) / 128, 256, 0, stream>>>(bm, bmT, k1T, N, F);

  k3_atom<<<1024, 256, 0, stream>>>(P1bf, P2bf, PBg, ewg, W2T,
                                    e_idx, e_type, e_attr, cda, ab2, aW3, agg, E);

  k2_frag<<<(N + 127) / 128, 256, 0, stream>>>(x_a, h_bf, k1T, agg, fW1aT, fW2T,
                                               fW1, fb1, fb2, fW3, out, N);
}

// Round 12
// 473.714 us; speedup vs baseline: 1.4553x; 1.4553x over previous
//
#include <hip/hip_runtime.h>
#include <hip/hip_bf16.h>

// EquivariantUpdate, round 12.
// prep -> pack_bmat -> k0_proj -> k1_gemm -> k3_atom -> k2_frag.
// K3 vs r11 (spill returned: (256,2) cap 128 < 64-reg upfront fa/fb + misc):
// rolling depth-1 prefetch in a #pragma unroll 1 kc-loop -> only 6 fragment
// regs live (24 VGPRs). Plain launch_bounds(256), grid 2048. PB stays
// global/L1 (r11's bank-conflict fix, confirmed CONFLICT=0).

typedef __attribute__((ext_vector_type(8))) short bfrag8;
typedef __attribute__((ext_vector_type(16))) float f32x16;
typedef __attribute__((ext_vector_type(4))) float f32x4v;

#define MFMA32(A, B, C) __builtin_amdgcn_mfma_f32_32x32x16_bf16((A), (B), (C), 0, 0, 0)

__device__ __forceinline__ f32x16 zero16() {
  f32x16 v;
#pragma unroll
  for (int i = 0; i < 16; ++i) v[i] = 0.0f;
  return v;
}

__device__ __forceinline__ unsigned short bf16bits(float x) {
  __hip_bfloat16 b = __float2bfloat16(x);
  unsigned short u;
  __builtin_memcpy(&u, &b, 2);
  return u;
}

__device__ __forceinline__ float b2f(unsigned short u) {
  unsigned x = ((unsigned)u) << 16;
  float f;
  __builtin_memcpy(&f, &x, 4);
  return f;
}

__device__ __forceinline__ unsigned pk2(float lo, float hi) {
  return (unsigned)bf16bits(lo) | ((unsigned)bf16bits(hi) << 16);
}

__device__ __forceinline__ bfrag8 ldfrag(const unsigned short* p) {
  return *reinterpret_cast<const bfrag8*>(p);
}

__device__ __forceinline__ bfrag8 frag4(unsigned f0, unsigned f1, unsigned f2, unsigned f3) {
  union { unsigned u[4]; bfrag8 v; } q;
  q.u[0] = f0; q.u[1] = f1; q.u[2] = f2; q.u[3] = f3;
  return q.v;
}

__device__ __forceinline__ float silu_f(float x) { return x / (1.0f + __expf(-x)); }

// ---------------- prep ----------------
// Segments: [cvt h_a][hfp][5x pack_wT][PB][ew][zero agg]
__global__ __launch_bounds__(256) void prep_kernel(
    const float* __restrict__ h_a, const float* __restrict__ bond,
    const float* __restrict__ h_f,
    const float* __restrict__ aW1, const float* __restrict__ ab1,
    const float* __restrict__ aW2,
    const float* __restrict__ fW1, const float* __restrict__ fW2,
    unsigned short* __restrict__ h_bf,
    float* __restrict__ hfp,
    unsigned short* __restrict__ W1aT, unsigned short* __restrict__ W1bT,
    unsigned short* __restrict__ W2T,
    unsigned short* __restrict__ fW1aT, unsigned short* __restrict__ fW2T,
    unsigned short* __restrict__ PBg, unsigned* __restrict__ ewg,
    float* __restrict__ agg,
    int N, int NB, int F) {
  const int t = threadIdx.x;
  int bid = blockIdx.x;
  const int G_A = (N * 16 + 255) >> 8;
  const int G_H = (F + 1) >> 1;
  const int G_PB = (NB * 128 + 255) >> 8;

  if (bid < G_A) {
    int idx = bid * 256 + t;
    if (idx < N * 16) {
      int row = idx >> 4, g = idx & 15;
      int h = g & 1, kc = g >> 1;
      const f32x4v* s = reinterpret_cast<const f32x4v*>(h_a + (size_t)row * 128 + g * 8);
      f32x4v v0 = s[0], v1 = s[1];
      unsigned* d = reinterpret_cast<unsigned*>(h_bf + (size_t)row * 128 + h * 64 + kc * 8);
      d[0] = pk2(v0[0], v0[1]);
      d[1] = pk2(v0[2], v0[3]);
      d[2] = pk2(v1[0], v1[1]);
      d[3] = pk2(v1[2], v1[3]);
    }
    return;
  }
  bid -= G_A;
  if (bid < G_H) {
    int f = bid * 2 + (t >> 7), n = t & 127;
    if (f < F) {
      float acc = 0.0f;
#pragma unroll 8
      for (int k = 0; k < 128; ++k)
        acc += h_f[(size_t)f * 128 + k] * fW1[(size_t)(128 + k) * 128 + n];
      hfp[(size_t)f * 128 + n] = acc;
    }
    return;
  }
  bid -= G_H;
  if (bid < 5 * 64) {
    int p = bid >> 6;
    int tt = (bid & 63) * 256 + t;
    int j = tt & 7, l = (tt >> 3) & 63, rem = tt >> 9;
    int nt = rem & 3, kc = rem >> 2;
    int k = kc * 16 + ((l >> 5) << 3) + j;
    int n = nt * 32 + (l & 31);
    const float* W;
    unsigned short* D;
    switch (p) {
      case 0: W = aW1;             D = W1aT;  break;
      case 1: W = aW1 + 128 * 128; D = W1bT;  break;
      case 2: W = aW2;             D = W2T;   break;
      case 3: W = fW1;             D = fW1aT; break;
      default: W = fW2;            D = fW2T;  break;
    }
    D[tt] = bf16bits(W[(size_t)k * 128 + n]);
    return;
  }
  bid -= 5 * 64;
  if (bid < G_PB) {
    // PB[t][n] = sum_m bond[t][m]*aW1[258+m][n] + ab1[n], stored bf16 permuted
    int idx = bid * 256 + t;
    if (idx < NB * 128) {
      int ty = idx >> 7, n = idx & 127;
      float acc = ab1[n];
#pragma unroll 8
      for (int m = 0; m < 128; ++m)
        acc += bond[(size_t)ty * 128 + m] * aW1[(size_t)(258 + m) * 128 + n];
      PBg[(size_t)ty * 128 + ((n >> 3) & 1) * 64 + (n >> 4) * 8 + (n & 7)] = bf16bits(acc);
    }
    return;
  }
  bid -= G_PB;
  if (bid < 1) {
    if (t < 128) {
      int k = t;
      unsigned u = pk2(aW1[(size_t)256 * 128 + k], aW1[(size_t)257 * 128 + k]);
      ewg[((k >> 4) * 2 + ((k >> 3) & 1)) * 8 + (k & 7)] = u;
    }
    return;
  }
  bid -= 1;
  {
    int i4 = (bid * 256 + t) * 4;
    if (i4 + 3 < N * 3) {
      *reinterpret_cast<f32x4v*>(agg + i4) = f32x4v{0.f, 0.f, 0.f, 0.f};
    } else {
      for (int c = 0; c < 4; ++c)
        if (i4 + c < N * 3) agg[i4 + c] = 0.0f;
    }
  }
}

// K1's A operand: Bmat^T frags.
__global__ void pack_bmat_kernel(const float* __restrict__ hfp, const float* __restrict__ x_f,
                                 unsigned short* __restrict__ dst, int total) {
  int t = blockIdx.x * blockDim.x + threadIdx.x;
  if (t >= total) return;
  int j = t & 7, l = (t >> 3) & 63, rem = t >> 9;
  int nt = rem % 5, kc = rem / 5;
  int k = kc * 16 + ((l >> 5) << 3) + j;
  int n = nt * 32 + (l & 31);
  float v;
  if (n < 128) v = hfp[(size_t)k * 128 + n];
  else if (n < 131) v = x_f[(size_t)k * 3 + (n - 128)];
  else v = 0.0f;
  dst[t] = bf16bits(v);
}

// ---------------- k0_proj: P1 = W1a^T h, P2 = W1b^T h (bf16, permuted) ----------------
__global__ __launch_bounds__(256) void k0_proj(
    const unsigned short* __restrict__ h_bf,
    const unsigned short* __restrict__ W1aT, const unsigned short* __restrict__ W1bT,
    unsigned short* __restrict__ P1bf, unsigned short* __restrict__ P2bf,
    int N) {
  const int lane = threadIdx.x & 63;
  const int w = threadIdx.x >> 6;
  const int h = lane >> 5;
  const int ln = lane & 31;
  const int node = blockIdx.x * 128 + w * 32 + ln;
  const int nc = (node < N) ? node : (N - 1);
  const unsigned short* hp = h_bf + (size_t)nc * 128 + h * 64;

#pragma unroll
  for (int p = 0; p < 2; ++p) {
    const unsigned short* WT = p ? W1bT : W1aT;
    unsigned short* dst = p ? P2bf : P1bf;
    f32x16 acc[4];
#pragma unroll
    for (int q = 0; q < 4; ++q) acc[q] = zero16();
#pragma unroll
    for (int kc = 0; kc < 8; ++kc) {
      bfrag8 b = ldfrag(hp + kc * 8);
      const unsigned short* wp = WT + ((size_t)(kc * 4) * 64 + lane) * 8;
#pragma unroll
      for (int nt = 0; nt < 4; ++nt) acc[nt] = MFMA32(ldfrag(wp + nt * 512), b, acc[nt]);
    }
    if (node < N) {
#pragma unroll
      for (int nt = 0; nt < 4; ++nt)
#pragma unroll
        for (int q = 0; q < 4; ++q) {
          union { unsigned u[2]; unsigned long long ull; } pr;
          pr.u[0] = pk2(acc[nt][4 * q + 0], acc[nt][4 * q + 1]);
          pr.u[1] = pk2(acc[nt][4 * q + 2], acc[nt][4 * q + 3]);
          int off = (q & 1) * 64 + (nt * 2 + (q >> 1)) * 8 + 4 * h;
          *reinterpret_cast<unsigned long long*>(dst + (size_t)node * 128 + off) = pr.ull;
        }
    }
  }
}

// ---------------- K1: barrier-free wave-private streaming GEMM ----------------
__global__ __launch_bounds__(256) void k1_gemm(
    const float* __restrict__ bm, const unsigned short* __restrict__ bmT,
    float* __restrict__ k1T, int N, int F) {
  __shared__ __align__(16) char lds[4][2][32 * 128];  // [wave][dbuf][4KB]
  const int t = threadIdx.x;
  const int lane = t & 63;
  const int w = t >> 6;
  const int h = lane >> 5;
  const int ln = lane & 31;
  const int m0w = blockIdx.x * 128 + w * 32;
  const int NT = (F + 63) >> 6;

  f32x16 acc[5];
#pragma unroll
  for (int i = 0; i < 5; ++i) acc[i] = zero16();

  int srow[8], sch[8];
  const float* sptr[8];
#pragma unroll
  for (int p = 0; p < 8; ++p) {
    int c = p * 64 + lane;
    srow[p] = c >> 4;
    sch[p] = c & 15;
    int gr = m0w + srow[p];
    if (gr >= N) gr = N - 1;
    sptr[p] = bm + (size_t)gr * F;
  }

  const int rsw = (ln & 7) << 4;

  f32x4v sregs[8];
#pragma unroll
  for (int p = 0; p < 8; ++p) {
    int gk = sch[p] * 4;
    if (gk > F - 4) gk = F - 4;
    sregs[p] = *reinterpret_cast<const f32x4v*>(sptr[p] + gk);
  }
#pragma unroll
  for (int p = 0; p < 8; ++p) {
    int byte = srow[p] * 128 + ((sch[p] * 8) ^ ((srow[p] & 7) << 4));
    union { unsigned u[2]; unsigned long long ull; } q;
    q.u[0] = pk2(sregs[p][0], sregs[p][1]);
    q.u[1] = pk2(sregs[p][2], sregs[p][3]);
    *reinterpret_cast<unsigned long long*>(&lds[w][0][byte]) = q.ull;
  }

  int cur = 0;
  for (int kt = 0; kt < NT; ++kt) {
    const bool more = (kt + 1 < NT);
    if (more) {
#pragma unroll
      for (int p = 0; p < 8; ++p) {
        int gk = (kt + 1) * 64 + sch[p] * 4;
        if (gk > F - 4) gk = F - 4;
        sregs[p] = *reinterpret_cast<const f32x4v*>(sptr[p] + gk);
      }
    }
    const int rem = (F - kt * 64) >> 4;
    const int kcN = rem < 4 ? rem : 4;
    if (kcN == 4) {
#pragma unroll
      for (int kc = 0; kc < 4; ++kc) {
        bfrag8 b = *reinterpret_cast<const bfrag8*>(
            &lds[w][cur][ln * 128 + ((kc * 32 + h * 16) ^ rsw)]);
        const unsigned short* wp = bmT + ((size_t)(kt * 4 + kc) * 5 * 64 + lane) * 8;
#pragma unroll
        for (int nt = 0; nt < 5; ++nt) acc[nt] = MFMA32(ldfrag(wp + nt * 512), b, acc[nt]);
      }
    } else {
      for (int kc = 0; kc < kcN; ++kc) {
        bfrag8 b = *reinterpret_cast<const bfrag8*>(
            &lds[w][cur][ln * 128 + ((kc * 32 + h * 16) ^ rsw)]);
        const unsigned short* wp = bmT + ((size_t)(kt * 4 + kc) * 5 * 64 + lane) * 8;
#pragma unroll
        for (int nt = 0; nt < 5; ++nt) acc[nt] = MFMA32(ldfrag(wp + nt * 512), b, acc[nt]);
      }
    }
    if (more) {
#pragma unroll
      for (int p = 0; p < 8; ++p) {
        int byte = srow[p] * 128 + ((sch[p] * 8) ^ ((srow[p] & 7) << 4));
        union { unsigned u[2]; unsigned long long ull; } q;
        q.u[0] = pk2(sregs[p][0], sregs[p][1]);
        q.u[1] = pk2(sregs[p][2], sregs[p][3]);
        *reinterpret_cast<unsigned long long*>(&lds[w][cur ^ 1][byte]) = q.ull;
      }
    }
    cur ^= 1;
  }

  const int m = m0w + ln;
  if (m < N) {
#pragma unroll
    for (int nt = 0; nt < 5; ++nt)
#pragma unroll
      for (int r = 0; r < 16; ++r) {
        int n = nt * 32 + (r & 3) + 8 * (r >> 2) + 4 * h;
        if (n < 131) k1T[(size_t)n * N + m] = acc[nt][r];
      }
  }
}

// ---------------- K3: edge MLP, rolling depth-1 prefetch, low-pressure ----------------
__global__ __launch_bounds__(256) void k3_atom(
    const unsigned short* __restrict__ P1bf, const unsigned short* __restrict__ P2bf,
    const unsigned short* __restrict__ PBg, const unsigned* __restrict__ ewg,
    const unsigned short* __restrict__ W2T,
    const int* __restrict__ eidx, const int* __restrict__ etype,
    const float* __restrict__ eattr, const float* __restrict__ cda,
    const float* __restrict__ ab2, const float* __restrict__ aW3,
    float* __restrict__ agg, int E) {
  __shared__ unsigned ew_lds[128];  // 512B; h-uniform reads -> broadcast
  if (threadIdx.x < 128) ew_lds[threadIdx.x] = ewg[threadIdx.x];
  __syncthreads();
  const uint4* ew4 = reinterpret_cast<const uint4*>(ew_lds);

  const int lane = threadIdx.x & 63;
  const int wid = threadIdx.x >> 6;
  const int h = lane >> 5;
  const int ln = lane & 31;
  const int nGroups = (E + 31) >> 5;
  const int stride = gridDim.x * 4;

  for (int g = blockIdx.x * 4 + wid; g < nGroups; g += stride) {
    const int e = g * 32 + ln;
    const bool valid = (e < E);
    const int ec = valid ? e : (E - 1);
    const int row = eidx[ec];
    const int col = eidx[(size_t)E + ec];
    const int typ = etype[ec];
    const float e0 = eattr[2 * (size_t)ec];
    const float e1 = eattr[2 * (size_t)ec + 1];

    const unsigned short* pr = P1bf + (size_t)row * 128 + h * 64;
    const unsigned short* pc = P2bf + (size_t)col * 128 + h * 64;
    const unsigned short* pb = PBg + (size_t)typ * 128 + h * 64;  // 25KB, L1-hot

    f32x16 acc[4];
#pragma unroll
    for (int q = 0; q < 4; ++q) acc[q] = zero16();

    // rolling depth-1 prefetch: only 6 fragment regs (24 VGPRs) live
    bfrag8 fa = ldfrag(pr), fb = ldfrag(pc), pv = ldfrag(pb);
#pragma unroll 1
    for (int kc = 0; kc < 8; ++kc) {
      bfrag8 fan = fa, fbn = fb, pvn = pv;
      if (kc < 7) {
        fan = ldfrag(pr + (kc + 1) * 8);
        fbn = ldfrag(pc + (kc + 1) * 8);
        pvn = ldfrag(pb + (kc + 1) * 8);
      }
      uint4 ea = ew4[(kc * 2 + h) * 2 + 0];
      uint4 eb = ew4[(kc * 2 + h) * 2 + 1];
      unsigned ew[8] = {ea.x, ea.y, ea.z, ea.w, eb.x, eb.y, eb.z, eb.w};
      float s[8];
#pragma unroll
      for (int j = 0; j < 8; ++j) {
        float z = b2f((unsigned short)fa[j]) + b2f((unsigned short)fb[j]) +
                  b2f((unsigned short)pv[j]) +
                  e0 * b2f((unsigned short)(ew[j] & 0xffffu)) +
                  e1 * b2f((unsigned short)(ew[j] >> 16));
        s[j] = silu_f(z);
      }
      bfrag8 b = frag4(pk2(s[0], s[1]), pk2(s[2], s[3]), pk2(s[4], s[5]), pk2(s[6], s[7]));
      const unsigned short* wp = W2T + ((size_t)(kc * 4) * 64 + lane) * 8;
#pragma unroll
      for (int nt = 0; nt < 4; ++nt) acc[nt] = MFMA32(ldfrag(wp + nt * 512), b, acc[nt]);
      fa = fan; fb = fbn; pv = pvn;
    }

    float part = 0.0f;
#pragma unroll
    for (int nt = 0; nt < 4; ++nt)
#pragma unroll
      for (int r = 0; r < 16; ++r) {
        int n = nt * 32 + (r & 3) + 8 * (r >> 2) + 4 * h;
        part += silu_f(acc[nt][r] + ab2[n]) * aW3[n];
      }
    float mv = part + __shfl_xor(part, 32);

    if (valid) {
      float tt = tanhf(mv) * 0.1f;  // *10 (COORDS_RANGE) / 100 (NORM_FACTOR)
      if (h == 0) {
        atomicAdd(agg + 3 * (size_t)row + 0, cda[3 * (size_t)ec + 0] * tt);
        atomicAdd(agg + 3 * (size_t)row + 1, cda[3 * (size_t)ec + 1] * tt);
      } else {
        atomicAdd(agg + 3 * (size_t)row + 2, cda[3 * (size_t)ec + 2] * tt);
      }
    }
  }
}

// ---------------- K2: fragment MLP + compose output ----------------
__global__ __launch_bounds__(256, 2) void k2_frag(
    const float* __restrict__ x_a, const unsigned short* __restrict__ h_bf,
    const float* __restrict__ k1T, const float* __restrict__ agg,
    const unsigned short* __restrict__ fW1aT, const unsigned short* __restrict__ fW2T,
    const float* __restrict__ fW1, const float* __restrict__ fb1,
    const float* __restrict__ fb2, const float* __restrict__ fW3,
    float* __restrict__ out, int N) {
  const int lane = threadIdx.x & 63;
  const int wid = threadIdx.x >> 6;
  const int h = lane >> 5;
  const int ln = lane & 31;
  const int i = blockIdx.x * 128 + wid * 32 + ln;
  const bool valid = (i < N);
  const int ic = valid ? i : (N - 1);

  float cd[3];
  float radial = 0.0f;
#pragma unroll
  for (int c = 0; c < 3; ++c) {
    float v = x_a[3 * (size_t)ic + c] - k1T[(size_t)(128 + c) * N + ic];
    cd[c] = v;
    radial += v * v;
  }

  f32x16 acc[4];
#pragma unroll
  for (int q = 0; q < 4; ++q) acc[q] = zero16();
  const unsigned short* hp = h_bf + (size_t)ic * 128 + h * 64;
#pragma unroll
  for (int kc = 0; kc < 8; ++kc) {
    bfrag8 b = ldfrag(hp + kc * 8);
    const unsigned short* wp = fW1aT + ((size_t)(kc * 4) * 64 + lane) * 8;
#pragma unroll
    for (int nt = 0; nt < 4; ++nt) acc[nt] = MFMA32(ldfrag(wp + nt * 512), b, acc[nt]);
  }

  unsigned wv[32];
#pragma unroll
  for (int nt = 0; nt < 4; ++nt)
#pragma unroll
    for (int p = 0; p < 8; ++p) {
      const int r0 = 2 * p;
      const int n0 = nt * 32 + (r0 & 3) + 8 * (r0 >> 2) + 4 * h;
      const int n1 = n0 + 1;
      float q0 = acc[nt][r0] + k1T[(size_t)n0 * N + ic]
               + radial * (fW1[(size_t)256 * 128 + n0] + fW1[(size_t)257 * 128 + n0]) + fb1[n0];
      float q1 = acc[nt][r0 + 1] + k1T[(size_t)n1 * N + ic]
               + radial * (fW1[(size_t)256 * 128 + n1] + fW1[(size_t)257 * 128 + n1]) + fb1[n1];
      wv[nt * 8 + p] = pk2(silu_f(q0), silu_f(q1));
    }

#pragma unroll
  for (int q = 0; q < 4; ++q) acc[q] = zero16();
#pragma unroll
  for (int kc = 0; kc < 8; ++kc) {
    const int base = (kc >> 1) * 8 + (kc & 1) * 4;
    unsigned a0 = wv[base + 0], a1 = wv[base + 1], a2 = wv[base + 2], a3 = wv[base + 3];
    unsigned s0 = (unsigned)__shfl_xor((int)a0, 32);
    unsigned s1 = (unsigned)__shfl_xor((int)a1, 32);
    unsigned s2 = (unsigned)__shfl_xor((int)a2, 32);
    unsigned s3 = (unsigned)__shfl_xor((int)a3, 32);
    bfrag8 b = frag4(h ? s2 : a0, h ? s3 : a1, h ? a2 : s0, h ? a3 : s1);
    const unsigned short* wp = fW2T + ((size_t)(kc * 4) * 64 + lane) * 8;
#pragma unroll
    for (int nt = 0; nt < 4; ++nt) acc[nt] = MFMA32(ldfrag(wp + nt * 512), b, acc[nt]);
  }

  float part = 0.0f;
#pragma unroll
  for (int nt = 0; nt < 4; ++nt)
#pragma unroll
    for (int r = 0; r < 16; ++r) {
      int n = nt * 32 + (r & 3) + 8 * (r >> 2) + 4 * h;
      part += silu_f(acc[nt][r] + fb2[n]) * fW3[n];
    }
  float mv = part + __shfl_xor(part, 32);

  if (valid && h == 0) {
    float nrm = sqrtf(radial + 1e-8f);
    float s = tanhf(mv) * 10.0f / (nrm + 1.0f);
#pragma unroll
    for (int c = 0; c < 3; ++c)
      out[3 * (size_t)i + c] = x_a[3 * (size_t)i + c] + cd[c] * s + agg[3 * (size_t)i + c];
  }
}

// ---------------- launch ----------------

extern "C" void kernel_launch(void* const* d_in, const int* in_sizes, int n_in,
                              void* d_out, int out_size, void* d_ws, size_t ws_size,
                              hipStream_t stream) {
  const float* h_a    = (const float*)d_in[0];
  const float* x_a    = (const float*)d_in[1];
  const int*   e_idx  = (const int*)d_in[2];
  const int*   e_type = (const int*)d_in[3];
  const float* e_attr = (const float*)d_in[4];
  const float* cda    = (const float*)d_in[5];
  const float* h_f    = (const float*)d_in[6];
  const float* x_f    = (const float*)d_in[7];
  const float* bm     = (const float*)d_in[8];
  const float* bond   = (const float*)d_in[9];
  const float* aW1    = (const float*)d_in[10];
  const float* ab1    = (const float*)d_in[11];
  const float* aW2    = (const float*)d_in[12];
  const float* ab2    = (const float*)d_in[13];
  const float* aW3    = (const float*)d_in[14];
  const float* fW1    = (const float*)d_in[15];
  const float* fb1    = (const float*)d_in[16];
  const float* fW2    = (const float*)d_in[17];
  const float* fb2    = (const float*)d_in[18];
  const float* fW3    = (const float*)d_in[19];
  float* out = (float*)d_out;

  const int N  = in_sizes[0] / 128;
  const int E  = in_sizes[2] / 2;
  const int F  = in_sizes[6] / 128;
  const int NB = in_sizes[9] / 128;
  const int KC = F / 16;

  char* wsp = (char*)d_ws;
  size_t off = 0;
  auto alloc = [&](size_t bytes) -> char* {
    char* p = wsp + off;
    off += (bytes + 255) & ~(size_t)255;
    return p;
  };
  unsigned short* h_bf  = (unsigned short*)alloc((size_t)N * 128 * 2);
  float*          hfp   = (float*)alloc((size_t)F * 128 * 4);
  unsigned short* bmT   = (unsigned short*)alloc((size_t)KC * 5 * 64 * 8 * 2);
  unsigned short* W1aT  = (unsigned short*)alloc(8 * 4 * 64 * 8 * 2);
  unsigned short* W1bT  = (unsigned short*)alloc(8 * 4 * 64 * 8 * 2);
  unsigned short* W2T   = (unsigned short*)alloc(8 * 4 * 64 * 8 * 2);
  unsigned short* fW1aT = (unsigned short*)alloc(8 * 4 * 64 * 8 * 2);
  unsigned short* fW2T  = (unsigned short*)alloc(8 * 4 * 64 * 8 * 2);
  unsigned short* PBg   = (unsigned short*)alloc((size_t)NB * 128 * 2);
  unsigned*       ewg   = (unsigned*)alloc(128 * 4);
  unsigned short* P1bf  = (unsigned short*)alloc((size_t)N * 128 * 2);
  unsigned short* P2bf  = (unsigned short*)alloc((size_t)N * 128 * 2);
  float*          k1T   = (float*)alloc((size_t)131 * N * 4);
  float*          agg   = (float*)alloc((size_t)N * 3 * 4);

  const int G_A  = (N * 16 + 255) >> 8;
  const int G_H  = (F + 1) >> 1;
  const int G_PB = (NB * 128 + 255) >> 8;
  const int G_Z  = (N * 3 + 1023) >> 10;
  prep_kernel<<<G_A + G_H + 5 * 64 + G_PB + 1 + G_Z, 256, 0, stream>>>(
      h_a, bond, h_f, aW1, ab1, aW2, fW1, fW2,
      h_bf, hfp, W1aT, W1bT, W2T, fW1aT, fW2T, PBg, ewg, agg,
      N, NB, F);

  {
    int total = KC * 5 * 64 * 8;
    pack_bmat_kernel<<<(total + 255) / 256, 256, 0, stream>>>(hfp, x_f, bmT, total);
  }

  k0_proj<<<(N + 127) / 128, 256, 0, stream>>>(h_bf, W1aT, W1bT, P1bf, P2bf, N);

  k1_gemm<<<(N + 127) / 128, 256, 0, stream>>>(bm, bmT, k1T, N, F);

  k3_atom<<<2048, 256, 0, stream>>>(P1bf, P2bf, PBg, ewg, W2T,
                                    e_idx, e_type, e_attr, cda, ab2, aW3, agg, E);

  k2_frag<<<(N + 127) / 128, 256, 0, stream>>>(x_a, h_bf, k1T, agg, fW1aT, fW2T,
                                               fW1, fb1, fb2, fW3, out, N);
}